// Round 1
// baseline (232.031 us; speedup 1.0000x reference)
//
#include <hip/hip_runtime.h>
#include <hip/hip_bf16.h>

// MaceEquivariantScorePredictionHead — MI355X (gfx950)
//
// Key algebraic reductions vs reference:
//  * s-path (x_s, W_tp0, Ws, batchnorm, silu) is dead code: output depends on v only.
//  * t = times @ W_time is rank-1 => TP collapses to v0 = times[n] * (x_v @ C1),
//    C1[v,o] = tp_norm * sum_u W_time[u]*W_tp1[u,v,o]  (fixed 128x128).
// Pipeline (all bf16 storage, f32 accum/stats):
//  K0: build frag-order bf16 B matrices (C1, Wv[i]*inv_sqrt_v)
//  K1: v0[m][n][o] GEMM from features (times folded at epilogue)
//  L x3: in-place (a[c] . v) @ Wv GEMM, accumulate per-channel sum(va^2)
//  F: scores[n,m] = sum_o va3 * (gamma/rms * Wr * inv_sqrt_v)

#define N_NODES 32768
#define NM (3 * N_NODES)

typedef __bf16 bf16_t;
typedef __bf16 bf16x8 __attribute__((ext_vector_type(8)));
typedef float f32x4 __attribute__((ext_vector_type(4)));

#define TP_NORM    0.022097086912079608f  /* 1/sqrt(16*128) */
#define INV_SQRT_V 0.08838834764831845f   /* 1/sqrt(128) */
#define EPSV       1e-5f

// workspace layout (elements of bf16 for V/BSW, then f32 ssq)
static constexpr size_t V_ELEMS   = (size_t)NM * 128;          // 12,582,912 bf16
static constexpr size_t BSW_ELEMS = 128 * 128;                 // per matrix
static constexpr size_t SSQ_BYTE_OFF = V_ELEMS * 2 + 4 * BSW_ELEMS * 2;

// ---------------------------------------------------------------- K0: weights
// Frag order for B (16x16x32 bf16 mfma): flat = ((ot*4+ks)*64 + lane)*8 + j
// value = B[k = ks*32 + (lane>>4)*8 + j][o = ot*16 + (lane&15)]
__global__ __launch_bounds__(256) void k_weights(
    const float* __restrict__ Wt, const float* __restrict__ Wtp1,
    const float* __restrict__ Wv, bf16_t* __restrict__ bsw) {
  int tid = blockIdx.x * 256 + threadIdx.x;   // 0..8191
  int mat = tid >> 11;                        // 0: C1(tp), 1..3: Wv[0..2]
  int idx = tid & 2047;                       // (ot*4+ks)*64 + lane
  int l = idx & 63;
  int o = ((idx >> 8) << 4) + (l & 15);
  int kbase = ((idx >> 6) & 3) * 32 + (l >> 4) * 8;
  bf16x8 out;
  if (mat == 0) {
#pragma unroll
    for (int j = 0; j < 8; ++j) {
      int k = kbase + j;
      float acc = 0.f;
#pragma unroll
      for (int u = 0; u < 16; ++u) acc += Wt[u] * Wtp1[(u * 128 + k) * 128 + o];
      out[j] = (bf16_t)(acc * TP_NORM);
    }
  } else {
#pragma unroll
    for (int j = 0; j < 8; ++j)
      out[j] = (bf16_t)(Wv[((mat - 1) * 128 + kbase + j) * 128 + o] * INV_SQRT_V);
  }
  *(bf16x8*)(bsw + (size_t)mat * BSW_ELEMS + idx * 8) = out;
}

// ---------------------------------------------------------------- K1: TP GEMM
// Block: 64 nodes, all 3 m-planes. A[m][node][v] = bf16(feat[n,128+3v+m]) in LDS
// (XOR-swizzled). v0[m][n][o] = times[n] * (A @ C1).
__global__ __launch_bounds__(256) void k_tp(
    const float* __restrict__ feat, const float* __restrict__ times,
    const bf16_t* __restrict__ bsw_tp, bf16_t* __restrict__ V) {
  __shared__ bf16_t A[3 * 64 * 128];
  __shared__ float tl[64];
  int t = threadIdx.x;
  int n0 = blockIdx.x * 64;
  if (t < 64) tl[t] = times[n0 + t];

  // stage: 4 threads per node, each covers 96 consecutive f32 of the x_v span
  int node = t >> 2, qt = t & 3;
  const float* src = feat + (size_t)(n0 + node) * 512 + 128 + qt * 96;
  char* Ab = (char*)A;
  int sw = (node & 7) << 4;
#pragma unroll
  for (int i = 0; i < 24; ++i) {
    float4 x4 = *(const float4*)(src + i * 4);
    float xs[4] = {x4.x, x4.y, x4.z, x4.w};
#pragma unroll
    for (int e = 0; e < 4; ++e) {
      int idx = qt * 96 + i * 4 + e;     // 0..383 = v*3 + m
      int v = idx / 3;
      int mm = idx - v * 3;
      int off = mm * 16384 + node * 256 + ((v * 2) ^ sw);
      *(bf16_t*)(Ab + off) = (bf16_t)xs[e];
    }
  }
  __syncthreads();

  int w = t >> 6, l = t & 63, lr = l & 15, lq = l >> 4;
  f32x4 acc[3][8];
#pragma unroll
  for (int m = 0; m < 3; ++m)
#pragma unroll
    for (int ot = 0; ot < 8; ++ot) acc[m][ot] = (f32x4){0.f, 0.f, 0.f, 0.f};

  int arow = w * 16 + lr;
  int asw = (arow & 7) << 4;
#pragma unroll
  for (int ks = 0; ks < 4; ++ks) {
    bf16x8 af[3];
#pragma unroll
    for (int m = 0; m < 3; ++m)
      af[m] = *(const bf16x8*)(Ab + m * 16384 + arow * 256 + ((ks * 64 + lq * 16) ^ asw));
#pragma unroll
    for (int ot = 0; ot < 8; ++ot) {
      bf16x8 bf = *(const bf16x8*)(bsw_tp + ((ot * 4 + ks) * 64 + l) * 8);
#pragma unroll
      for (int m = 0; m < 3; ++m)
        acc[m][ot] = __builtin_amdgcn_mfma_f32_16x16x32_bf16(af[m], bf, acc[m][ot], 0, 0, 0);
    }
  }
  // epilogue: fold times[n], write bf16
#pragma unroll
  for (int m = 0; m < 3; ++m)
#pragma unroll
    for (int ot = 0; ot < 8; ++ot)
#pragma unroll
      for (int i = 0; i < 4; ++i) {
        int nd = w * 16 + lq * 4 + i;
        float val = acc[m][ot][i] * tl[nd];
        V[((size_t)m * N_NODES + n0 + nd) * 128 + ot * 16 + lr] = (bf16_t)val;
      }
}

// ---------------------------------------------------------------- L: layer GEMM
// In-place: block owns 128 rows of one m-plane. A-stage applies per-channel a[c].
// Accumulates sum(va^2) per output channel into ssq_out (global atomics).
__global__ __launch_bounds__(256) void k_layer(
    bf16_t* __restrict__ V, const bf16_t* __restrict__ bsw,
    const float* __restrict__ ssq_in, const float* __restrict__ gamma_in,
    float* __restrict__ ssq_out) {
  __shared__ bf16_t A[128 * 128];
  __shared__ float a_lds[128];
  __shared__ float red[4][128];
  int t = threadIdx.x;
  int m = blockIdx.x >> 8;
  int n0 = (blockIdx.x & 255) * 128;
  if (t < 128) {
    float a = 1.f;
    if (ssq_in) a = gamma_in[t] * rsqrtf(ssq_in[t] * (1.f / NM) + EPSV);
    a_lds[t] = a;
  }
  __syncthreads();

  bf16_t* src = V + ((size_t)m * N_NODES + n0) * 128;
  char* Ab = (char*)A;
#pragma unroll
  for (int i = 0; i < 8; ++i) {
    int chunk = t + i * 256;          // 0..2047 chunks of 16B
    int row = chunk >> 4, c16 = chunk & 15;
    bf16x8 x = *(const bf16x8*)(src + row * 128 + c16 * 8);
    bf16x8 y;
#pragma unroll
    for (int j = 0; j < 8; ++j) y[j] = (bf16_t)((float)x[j] * a_lds[c16 * 8 + j]);
    *(bf16x8*)(Ab + row * 256 + ((c16 * 16) ^ ((row & 7) << 4))) = y;
  }
  __syncthreads();

  int w = t >> 6, l = t & 63, lr = l & 15, lq = l >> 4;
  f32x4 acc[2][8];
#pragma unroll
  for (int rt = 0; rt < 2; ++rt)
#pragma unroll
    for (int ot = 0; ot < 8; ++ot) acc[rt][ot] = (f32x4){0.f, 0.f, 0.f, 0.f};

#pragma unroll
  for (int ks = 0; ks < 4; ++ks) {
    bf16x8 af[2];
#pragma unroll
    for (int rt = 0; rt < 2; ++rt) {
      int row = w * 32 + rt * 16 + lr;
      af[rt] = *(const bf16x8*)(Ab + row * 256 + ((ks * 64 + lq * 16) ^ ((row & 7) << 4)));
    }
#pragma unroll
    for (int ot = 0; ot < 8; ++ot) {
      bf16x8 bf = *(const bf16x8*)(bsw + ((ot * 4 + ks) * 64 + l) * 8);
      acc[0][ot] = __builtin_amdgcn_mfma_f32_16x16x32_bf16(af[0], bf, acc[0][ot], 0, 0, 0);
      acc[1][ot] = __builtin_amdgcn_mfma_f32_16x16x32_bf16(af[1], bf, acc[1][ot], 0, 0, 0);
    }
  }

  // per-channel sum of squares (f32, pre-rounding) + in-place bf16 write
#pragma unroll
  for (int ot = 0; ot < 8; ++ot) {
    float s = 0.f;
#pragma unroll
    for (int rt = 0; rt < 2; ++rt)
#pragma unroll
      for (int i = 0; i < 4; ++i) s += acc[rt][ot][i] * acc[rt][ot][i];
    s += __shfl_xor(s, 16);
    s += __shfl_xor(s, 32);
    if (lq == 0) red[w][ot * 16 + lr] = s;
  }
#pragma unroll
  for (int rt = 0; rt < 2; ++rt)
#pragma unroll
    for (int ot = 0; ot < 8; ++ot)
#pragma unroll
      for (int i = 0; i < 4; ++i) {
        int row = w * 32 + rt * 16 + lq * 4 + i;
        V[((size_t)m * N_NODES + n0 + row) * 128 + ot * 16 + lr] = (bf16_t)acc[rt][ot][i];
      }
  __syncthreads();
  if (t < 128) {
    float s = red[0][t] + red[1][t] + red[2][t] + red[3][t];
    atomicAdd(ssq_out + t, s);
  }
}

// ---------------------------------------------------------------- F: final dot
__global__ __launch_bounds__(256) void k_final(
    const bf16_t* __restrict__ V, const float* __restrict__ ssq,
    const float* __restrict__ gamma, const float* __restrict__ Wr,
    float* __restrict__ out) {
  __shared__ float wl[128];
  int t = threadIdx.x;
  if (t < 128)
    wl[t] = gamma[t] * rsqrtf(ssq[t] * (1.f / NM) + EPSV) * Wr[t] * INV_SQRT_V;
  __syncthreads();
  int row = blockIdx.x * 64 + (t >> 2);  // row in [0, 3N): row = m*N + n
  int q = t & 3;
  const bf16_t* src = V + (size_t)row * 128 + q * 32;
  float s = 0.f;
#pragma unroll
  for (int i = 0; i < 4; ++i) {
    bf16x8 x = *(const bf16x8*)(src + i * 8);
#pragma unroll
    for (int j = 0; j < 8; ++j) s += (float)x[j] * wl[q * 32 + i * 8 + j];
  }
  s += __shfl_xor(s, 1);
  s += __shfl_xor(s, 2);
  if (q == 0) {
    int mm = row / N_NODES;
    int n = row & (N_NODES - 1);
    out[n * 3 + mm] = s;
  }
}

// ---------------------------------------------------------------- launch
extern "C" void kernel_launch(void* const* d_in, const int* in_sizes, int n_in,
                              void* d_out, int out_size, void* d_ws, size_t ws_size,
                              hipStream_t stream) {
  const float* feat  = (const float*)d_in[0];
  const float* times = (const float*)d_in[1];
  const float* Wt    = (const float*)d_in[2];
  const float* Wtp1  = (const float*)d_in[4];   // W_tp1 (W_tp0 unused: s-path dead)
  const float* Wv    = (const float*)d_in[6];
  const float* gv    = (const float*)d_in[9];
  const float* Wr    = (const float*)d_in[10];
  float* out = (float*)d_out;

  bf16_t* V   = (bf16_t*)d_ws;
  bf16_t* bsw = V + V_ELEMS;
  float* ssq  = (float*)((char*)d_ws + SSQ_BYTE_OFF);

  hipMemsetAsync(ssq, 0, 3 * 128 * sizeof(float), stream);
  k_weights<<<32, 256, 0, stream>>>(Wt, Wtp1, Wv, bsw);
  k_tp<<<N_NODES / 64, 256, 0, stream>>>(feat, times, bsw, V);
  k_layer<<<768, 256, 0, stream>>>(V, bsw + 1 * BSW_ELEMS, nullptr, nullptr, ssq);
  k_layer<<<768, 256, 0, stream>>>(V, bsw + 2 * BSW_ELEMS, ssq, gv, ssq + 128);
  k_layer<<<768, 256, 0, stream>>>(V, bsw + 3 * BSW_ELEMS, ssq + 128, gv + 128, ssq + 256);
  k_final<<<NM / 64, 256, 0, stream>>>(V, ssq + 256, gv + 256, Wr, out);
}

// Round 2
// 226.517 us; speedup vs baseline: 1.0243x; 1.0243x over previous
//
#include <hip/hip_runtime.h>
#include <hip/hip_bf16.h>

// MaceEquivariantScorePredictionHead — MI355X (gfx950)
//
// Algebraic reductions:
//  * s-path is dead code (output depends on v only).
//  * t = times @ W_time is rank-1 => v0 = times[n] * (x_v @ C1),
//    C1[v,o] = tp_norm * sum_u W_time[u]*W_tp1[u,v,o]  (fixed 128x128).
// All GEMMs use SWAPPED mfma operands (C^T = W^T X^T) so each lane holds 4
// contiguous output channels -> vectorized stores.

#define N_NODES 32768
#define NM (3 * N_NODES)

typedef __bf16 bf16_t;
typedef __bf16 bf16x4 __attribute__((ext_vector_type(4)));
typedef __bf16 bf16x8 __attribute__((ext_vector_type(8)));
typedef float f32x4 __attribute__((ext_vector_type(4)));

#define TP_NORM    0.022097086912079608f  /* 1/sqrt(16*128) */
#define INV_SQRT_V 0.08838834764831845f   /* 1/sqrt(128) */
#define EPSV       1e-5f

static constexpr size_t V_ELEMS   = (size_t)NM * 128;
static constexpr size_t BSW_ELEMS = 128 * 128;
static constexpr size_t SSQ_BYTE_OFF = V_ELEMS * 2 + 4 * BSW_ELEMS * 2;

// ---------------------------------------------------------------- K0: weights
// Frag order: flat = ((ot*4+ks)*64 + lane)*8 + j
// value = B[k = ks*32 + (lane>>4)*8 + j][o = ot*16 + (lane&15)]
// blocks 0..63: C1 (two k-rows per block, coalesced Wtp1 reads)
// blocks 64..87: Wv mats (frag-gather from L2-cached 192KB)
__global__ __launch_bounds__(256) void k_weights(
    const float* __restrict__ Wt, const float* __restrict__ Wtp1,
    const float* __restrict__ Wv, bf16_t* __restrict__ bsw) {
  int b = blockIdx.x, t = threadIdx.x;
  if (b < 64) {
    int k = 2 * b + (t >> 7);
    int o = t & 127;
    float acc = 0.f;
#pragma unroll
    for (int u = 0; u < 16; ++u) acc += Wt[u] * Wtp1[(u * 128 + k) * 128 + o];
    int ks = k >> 5, hi = (k >> 3) & 3, j = k & 7;
    int l = hi * 16 + (o & 15), ot = o >> 4;
    bsw[((ot * 4 + ks) * 64 + l) * 8 + j] = (bf16_t)(acc * TP_NORM);
  } else {
    int vid = (b - 64) * 256 + t;            // 0..6143
    int mat = 1 + (vid >> 11);
    int idx = vid & 2047;
    int l = idx & 63;
    int o = ((idx >> 8) << 4) + (l & 15);
    int kbase = ((idx >> 6) & 3) * 32 + (l >> 4) * 8;
    bf16x8 out;
#pragma unroll
    for (int j = 0; j < 8; ++j)
      out[j] = (bf16_t)(Wv[((mat - 1) * 128 + kbase + j) * 128 + o] * INV_SQRT_V);
    *(bf16x8*)(bsw + (size_t)mat * BSW_ELEMS + (size_t)idx * 8) = out;
  }
}

// ---------------------------------------------------------------- K1: TP GEMM
// Block: 64 nodes. Coalesced float4 sweep of x_v region -> raw interleaved
// bf16 rows in LDS (stride 784B). Frag-build de-interleaves stride-3 via
// 3x ds_read_b128 + compile-time shuffles (one 48B window serves all 3 m).
// mfma(C1_frag, x_frag, acc) => lane holds 4 contiguous o -> 8B stores.
__global__ __launch_bounds__(256) void k_tp(
    const float* __restrict__ feat, const float* __restrict__ times,
    const bf16_t* __restrict__ bsw_tp, bf16_t* __restrict__ V) {
  __shared__ char Ab[64 * 784];   // 64 rows x 384 bf16 (+16B pad)
  __shared__ float tl[64];
  int t = threadIdx.x;
  int n0 = blockIdx.x * 64;
  if (t < 64) tl[t] = times[n0 + t];

  // stage: 6144 float4 chunks, fully coalesced
#pragma unroll
  for (int i = 0; i < 24; ++i) {
    int idx = i * 256 + t;
    int row = idx / 96;
    int c4 = idx - row * 96;
    float4 x = *(const float4*)(feat + (size_t)(n0 + row) * 512 + 128 + c4 * 4);
    bf16x4 b4 = {(bf16_t)x.x, (bf16_t)x.y, (bf16_t)x.z, (bf16_t)x.w};
    *(bf16x4*)(Ab + row * 784 + c4 * 8) = b4;
  }
  __syncthreads();

  int w = t >> 6, l = t & 63, lr = l & 15, lq = l >> 4;
  int node = w * 16 + lr;                     // B-frag col = node
  f32x4 acc[3][8];
#pragma unroll
  for (int m = 0; m < 3; ++m)
#pragma unroll
    for (int ot = 0; ot < 8; ++ot) acc[m][ot] = (f32x4){0.f, 0.f, 0.f, 0.f};

#pragma unroll
  for (int ks = 0; ks < 4; ++ks) {
    const char* p = Ab + node * 784 + 192 * ks + 48 * lq;
    bf16x8 r0 = *(const bf16x8*)(p);
    bf16x8 r1 = *(const bf16x8*)(p + 16);
    bf16x8 r2 = *(const bf16x8*)(p + 32);
    bf16x8 xf[3];
#pragma unroll
    for (int m = 0; m < 3; ++m)
#pragma unroll
      for (int j = 0; j < 8; ++j) {
        int s = 3 * j + m;
        xf[m][j] = s < 8 ? r0[s] : (s < 16 ? r1[s - 8] : r2[s - 16]);
      }
#pragma unroll
    for (int ot = 0; ot < 8; ++ot) {
      bf16x8 wf = *(const bf16x8*)(bsw_tp + ((ot * 4 + ks) * 64 + l) * 8);
#pragma unroll
      for (int m = 0; m < 3; ++m)
        acc[m][ot] = __builtin_amdgcn_mfma_f32_16x16x32_bf16(wf, xf[m], acc[m][ot], 0, 0, 0);
    }
  }

  // epilogue: C^T layout -> lane holds o = ot*16 + lq*4 + (0..3) at col n=node
  float tv = tl[node];
#pragma unroll
  for (int m = 0; m < 3; ++m)
#pragma unroll
    for (int ot = 0; ot < 8; ++ot) {
      bf16x4 b4;
#pragma unroll
      for (int i = 0; i < 4; ++i) b4[i] = (bf16_t)(acc[m][ot][i] * tv);
      *(bf16x4*)(V + ((size_t)m * N_NODES + n0 + node) * 128 + ot * 16 + lq * 4) = b4;
    }
}

// ---------------------------------------------------------------- L: layer GEMM
// In-place 128-row tile of one m-plane. A-stage applies per-channel scale,
// XOR-swizzled. Swapped mfma => LDS transpose epilogue with coalesced
// dwordx4 stores; ssq computed during readback.
__global__ __launch_bounds__(256) void k_layer(
    bf16_t* __restrict__ V, const bf16_t* __restrict__ bsw,
    const float* __restrict__ ssq_in, const float* __restrict__ gamma_in,
    float* __restrict__ ssq_out) {
  __shared__ char Ab[128 * 272];     // union: A-stage (128*256) / C^T transpose (128*272)
  __shared__ float a_lds[128];
  __shared__ float red[16 * 132];
  int t = threadIdx.x;
  int m = blockIdx.x >> 8;
  int n0 = (blockIdx.x & 255) * 128;
  if (t < 128) {
    float a = 1.f;
    if (ssq_in) a = gamma_in[t] * rsqrtf(ssq_in[t] * (1.f / NM) + EPSV);
    a_lds[t] = a;
  }
  __syncthreads();

  bf16_t* src = V + ((size_t)m * N_NODES + n0) * 128;
#pragma unroll
  for (int i = 0; i < 8; ++i) {
    int chunk = t + i * 256;
    int row = chunk >> 4, c16 = chunk & 15;
    bf16x8 x = *(const bf16x8*)(src + row * 128 + c16 * 8);
    bf16x8 y;
#pragma unroll
    for (int j = 0; j < 8; ++j) y[j] = (bf16_t)((float)x[j] * a_lds[c16 * 8 + j]);
    *(bf16x8*)(Ab + row * 256 + ((c16 * 16) ^ ((row & 7) << 4))) = y;
  }
  __syncthreads();

  int w = t >> 6, l = t & 63, lr = l & 15, lq = l >> 4;
  f32x4 acc[2][8];
#pragma unroll
  for (int nt = 0; nt < 2; ++nt)
#pragma unroll
    for (int ot = 0; ot < 8; ++ot) acc[nt][ot] = (f32x4){0.f, 0.f, 0.f, 0.f};

#pragma unroll
  for (int ks = 0; ks < 4; ++ks) {
    bf16x8 xf[2];
#pragma unroll
    for (int nt = 0; nt < 2; ++nt) {
      int row = (2 * w + nt) * 16 + lr;
      xf[nt] = *(const bf16x8*)(Ab + row * 256 + ((ks * 64 + lq * 16) ^ ((row & 7) << 4)));
    }
#pragma unroll
    for (int ot = 0; ot < 8; ++ot) {
      bf16x8 wf = *(const bf16x8*)(bsw + ((ot * 4 + ks) * 64 + l) * 8);
      acc[0][ot] = __builtin_amdgcn_mfma_f32_16x16x32_bf16(wf, xf[0], acc[0][ot], 0, 0, 0);
      acc[1][ot] = __builtin_amdgcn_mfma_f32_16x16x32_bf16(wf, xf[1], acc[1][ot], 0, 0, 0);
    }
  }
  __syncthreads();   // done reading A-stage; reuse as transpose buffer

  // write C^T into LDS transpose buffer: T[n_local][o], stride 272B
#pragma unroll
  for (int nt = 0; nt < 2; ++nt) {
    int nl = (2 * w + nt) * 16 + lr;
#pragma unroll
    for (int ot = 0; ot < 8; ++ot) {
      bf16x4 b4;
#pragma unroll
      for (int i = 0; i < 4; ++i) b4[i] = (bf16_t)(acc[nt][ot][i]);
      *(bf16x4*)(Ab + nl * 272 + (ot * 16 + lq * 4) * 2) = b4;
    }
  }
  __syncthreads();

  // coalesced readback -> global; per-channel ssq on the fly
  int c16 = t & 15;                  // fixed channel octet per thread
  float p[8];
#pragma unroll
  for (int j = 0; j < 8; ++j) p[j] = 0.f;
#pragma unroll
  for (int i = 0; i < 8; ++i) {
    int nl = i * 16 + (t >> 4);
    bf16x8 v8 = *(const bf16x8*)(Ab + nl * 272 + c16 * 16);
    *(bf16x8*)(V + ((size_t)m * N_NODES + n0 + nl) * 128 + c16 * 8) = v8;
#pragma unroll
    for (int j = 0; j < 8; ++j) { float f = (float)v8[j]; p[j] += f * f; }
  }
#pragma unroll
  for (int j = 0; j < 8; ++j) red[(t >> 4) * 132 + c16 * 8 + j] = p[j];
  __syncthreads();
  if (t < 128) {
    float s = 0.f;
#pragma unroll
    for (int g = 0; g < 16; ++g) s += red[g * 132 + t];
    atomicAdd(ssq_out + t, s);
  }
}

// ---------------------------------------------------------------- F: final dot
__global__ __launch_bounds__(256) void k_final(
    const bf16_t* __restrict__ V, const float* __restrict__ ssq,
    const float* __restrict__ gamma, const float* __restrict__ Wr,
    float* __restrict__ out) {
  __shared__ float wl[128];
  int t = threadIdx.x;
  if (t < 128)
    wl[t] = gamma[t] * rsqrtf(ssq[t] * (1.f / NM) + EPSV) * Wr[t] * INV_SQRT_V;
  __syncthreads();
  int row = blockIdx.x * 64 + (t >> 2);  // row = m*N + n
  int q = t & 3;
  const bf16_t* src = V + (size_t)row * 128 + q * 32;
  float s = 0.f;
#pragma unroll
  for (int i = 0; i < 4; ++i) {
    bf16x8 x = *(const bf16x8*)(src + i * 8);
#pragma unroll
    for (int j = 0; j < 8; ++j) s += (float)x[j] * wl[q * 32 + i * 8 + j];
  }
  s += __shfl_xor(s, 1);
  s += __shfl_xor(s, 2);
  if (q == 0) {
    int mm = row / N_NODES;
    int n = row & (N_NODES - 1);
    out[n * 3 + mm] = s;
  }
}

// ---------------------------------------------------------------- launch
extern "C" void kernel_launch(void* const* d_in, const int* in_sizes, int n_in,
                              void* d_out, int out_size, void* d_ws, size_t ws_size,
                              hipStream_t stream) {
  const float* feat  = (const float*)d_in[0];
  const float* times = (const float*)d_in[1];
  const float* Wt    = (const float*)d_in[2];
  const float* Wtp1  = (const float*)d_in[4];
  const float* Wv    = (const float*)d_in[6];
  const float* gv    = (const float*)d_in[9];
  const float* Wr    = (const float*)d_in[10];
  float* out = (float*)d_out;

  bf16_t* V   = (bf16_t*)d_ws;
  bf16_t* bsw = V + V_ELEMS;
  float* ssq  = (float*)((char*)d_ws + SSQ_BYTE_OFF);

  hipMemsetAsync(ssq, 0, 3 * 128 * sizeof(float), stream);
  k_weights<<<88, 256, 0, stream>>>(Wt, Wtp1, Wv, bsw);
  k_tp<<<N_NODES / 64, 256, 0, stream>>>(feat, times, bsw, V);
  k_layer<<<768, 256, 0, stream>>>(V, bsw + 1 * BSW_ELEMS, nullptr, nullptr, ssq);
  k_layer<<<768, 256, 0, stream>>>(V, bsw + 2 * BSW_ELEMS, ssq, gv, ssq + 128);
  k_layer<<<768, 256, 0, stream>>>(V, bsw + 3 * BSW_ELEMS, ssq + 128, gv + 128, ssq + 256);
  k_final<<<NM / 64, 256, 0, stream>>>(V, ssq + 256, gv + 256, Wr, out);
}